// Round 4
// baseline (2025.718 us; speedup 1.0000x reference)
//
#include <hip/hip_runtime.h>
#include <math.h>

#define GRID_SZ 128
#define NC 196
#define NC4 49                // NC/4 float4 per row
#define G2 (GRID_SZ*GRID_SZ)  // 16384
#define PPW 64                // points per wave
#define BLK_WAVES 4
#define ENTRIES (BLK_WAVES*9) // 4 waves x 3 planes x 3 slots = 36
#define EROW 200              // floats per LDS entry row (196 acc + den + pad, 16B-aligned)

struct Slot {
    int tag;      // GLOBAL tag = (bb*3+plane)*G2 + cell ; -1 = empty
    float den;    // accumulated alpha (wave-uniform value)
    float4 acc;   // this lane's 4 channels' accumulated alpha*feat
};

// ---------- cell-major (workspace) path ----------

__device__ __forceinline__ void slot_flush_g(const Slot& s, float* __restrict__ nw,
                                             float* __restrict__ dn, int lane) {
    if (s.tag < 0) return;
    if (lane < NC4) {
        float* base = nw + (size_t)s.tag * NC + 4 * lane;
        unsafeAtomicAdd(base + 0, s.acc.x);
        unsafeAtomicAdd(base + 1, s.acc.y);
        unsafeAtomicAdd(base + 2, s.acc.z);
        unsafeAtomicAdd(base + 3, s.acc.w);
    } else if (lane == NC4) {
        unsafeAtomicAdd(dn + s.tag, s.den);
    }
}

// 3-slot cache, min-den eviction: keeps the (data-dependent) hot cells resident.
__device__ __forceinline__ void plane_acc3(Slot& a, Slot& b, Slot& c,
                                           int gtag, float alpha, const float4& av,
                                           float* __restrict__ nw, float* __restrict__ dn,
                                           int lane) {
    if (gtag == a.tag) {
        a.acc.x += av.x; a.acc.y += av.y; a.acc.z += av.z; a.acc.w += av.w;
        a.den += alpha;
    } else if (gtag == b.tag) {
        b.acc.x += av.x; b.acc.y += av.y; b.acc.z += av.z; b.acc.w += av.w;
        b.den += alpha;
    } else if (gtag == c.tag) {
        c.acc.x += av.x; c.acc.y += av.y; c.acc.z += av.z; c.acc.w += av.w;
        c.den += alpha;
    } else {
        // evict the lightest slot (wave-uniform branch)
        if (c.den <= a.den && c.den <= b.den) {
            slot_flush_g(c, nw, dn, lane);
            c.tag = gtag; c.den = alpha; c.acc = av;
        } else if (b.den <= a.den) {
            slot_flush_g(b, nw, dn, lane);
            b.tag = gtag; b.den = alpha; b.acc = av;
        } else {
            slot_flush_g(a, nw, dn, lane);
            a.tag = gtag; a.den = alpha; a.acc = av;
        }
    }
}

__device__ __forceinline__ void slot_to_lds(const Slot& s, int e,
                                            float* lacc, int* ltag, int lane) {
    if (lane < NC4) *(float4*)&lacc[e * EROW + 4 * lane] = s.acc;
    if (lane == NC4) lacc[e * EROW + NC] = s.den;
    if (lane == 0) ltag[e] = s.tag;
}

__global__ __launch_bounds__(256) void splat_cm_kernel(
    const float* __restrict__ gs, const float* __restrict__ sb,
    float* __restrict__ nw, float* __restrict__ dn,
    int B, int N) {
    __shared__ float lacc[ENTRIES * EROW];
    __shared__ int ltag[ENTRIES];

    const int lane = threadIdx.x & 63;
    const int widx = threadIdx.x >> 6;
    const long long wave = (long long)blockIdx.x * BLK_WAVES + widx;
    const long long totalPts = (long long)B * N;
    long long start = wave * PPW;
    const bool active = (start < totalPts);

    const float4 f40 = make_float4(0.f, 0.f, 0.f, 0.f);
    Slot a0{-1, 0.f, f40}, b0{-1, 0.f, f40}, c0{-1, 0.f, f40};
    Slot a1{-1, 0.f, f40}, b1{-1, 0.f, f40}, c1{-1, 0.f, f40};
    Slot a2{-1, 0.f, f40}, b2{-1, 0.f, f40}, c2{-1, 0.f, f40};

    if (active) {
        long long end = start + PPW;
        if (end > totalPts) end = totalPts;
        const int bb = (int)(start / N);

        const float lo0 = sb[0], hi0 = sb[1];
        const float lo1 = sb[2], hi1 = sb[3];
        const float lo2 = sb[4], hi2 = sb[5];
        const float s0 = 2.0f / (hi0 - lo0);
        const float s1 = 2.0f / (hi1 - lo1);
        const float s2 = 2.0f / (hi2 - lo2);

        const int db0 = (bb * 3 + 0) * G2;
        const int db1 = (bb * 3 + 1) * G2;
        const int db2 = (bb * 3 + 2) * G2;

        const float4* rows = (const float4*)gs;
        const float4* r0 = rows + (size_t)start * NC4;
        float4 v = (lane < NC4) ? r0[lane] : f40;
        float4 h = r0[0];

        for (long long i = start; i < end; ++i) {
            float4 vn = f40, hn = f40;
            if (i + 1 < end) {
                const float4* rn = rows + (size_t)(i + 1) * NC4;
                vn = (lane < NC4) ? rn[lane] : f40;
                hn = rn[0];
            }

            const float cnx = (h.x - lo0) * s0 - 1.0f;
            const float cny = (h.y - lo1) * s1 - 1.0f;
            const float cnz = (h.z - lo2) * s2 - 1.0f;
            int gx = (int)((cnx * 0.5f + 0.5f) * 127.0f);
            int gy = (int)((cny * 0.5f + 0.5f) * 127.0f);
            int gz = (int)((cnz * 0.5f + 0.5f) * 127.0f);
            gx = min(127, max(0, gx));
            gy = min(127, max(0, gy));
            gz = min(127, max(0, gz));
            const int txy = db0 + __builtin_amdgcn_readfirstlane(gx * GRID_SZ + gy);
            const int txz = db1 + __builtin_amdgcn_readfirstlane(gx * GRID_SZ + gz);
            const int tyz = db2 + __builtin_amdgcn_readfirstlane(gy * GRID_SZ + gz);

            const float alpha = 1.0f / (1.0f + __expf(-h.w));

            float4 vv = v;
            if (lane == 0) { vv.x = cnx; vv.y = cny; vv.z = cnz; }
            const float4 av = make_float4(vv.x * alpha, vv.y * alpha, vv.z * alpha, vv.w * alpha);

            plane_acc3(a0, b0, c0, txy, alpha, av, nw, dn, lane);
            plane_acc3(a1, b1, c1, txz, alpha, av, nw, dn, lane);
            plane_acc3(a2, b2, c2, tyz, alpha, av, nw, dn, lane);

            v = vn; h = hn;
        }
    }

    // dump the 9 slots to LDS for block-level dedupe of end-of-wave flushes
    const int ebase = widx * 9;
    slot_to_lds(a0, ebase + 0, lacc, ltag, lane);
    slot_to_lds(b0, ebase + 1, lacc, ltag, lane);
    slot_to_lds(c0, ebase + 2, lacc, ltag, lane);
    slot_to_lds(a1, ebase + 3, lacc, ltag, lane);
    slot_to_lds(b1, ebase + 4, lacc, ltag, lane);
    slot_to_lds(c1, ebase + 5, lacc, ltag, lane);
    slot_to_lds(a2, ebase + 6, lacc, ltag, lane);
    slot_to_lds(b2, ebase + 7, lacc, ltag, lane);
    slot_to_lds(c2, ebase + 8, lacc, ltag, lane);
    __syncthreads();

    // each wave merges+flushes its 9 entries; first-occurrence entry owns the tag
    for (int e = ebase; e < ebase + 9; ++e) {
        const int t = ltag[e];
        if (t < 0) continue;
        bool dup = false;
        for (int e2 = 0; e2 < e; ++e2) dup = dup || (ltag[e2] == t);
        if (dup) continue;

        float4 a = f40;
        if (lane < NC4) a = *(const float4*)&lacc[e * EROW + 4 * lane];
        float d = lacc[e * EROW + NC];
        for (int e2 = e + 1; e2 < ENTRIES; ++e2) {
            if (ltag[e2] == t) {
                if (lane < NC4) {
                    float4 x = *(const float4*)&lacc[e2 * EROW + 4 * lane];
                    a.x += x.x; a.y += x.y; a.z += x.z; a.w += x.w;
                }
                d += lacc[e2 * EROW + NC];
            }
        }
        if (lane < NC4) {
            float* base = nw + (size_t)t * NC + 4 * lane;
            unsafeAtomicAdd(base + 0, a.x);
            unsafeAtomicAdd(base + 1, a.y);
            unsafeAtomicAdd(base + 2, a.z);
            unsafeAtomicAdd(base + 3, a.w);
        } else if (lane == NC4) {
            unsafeAtomicAdd(dn + t, d);
        }
    }
}

#define TCELLS 64
__global__ __launch_bounds__(256) void xpose_kernel(const float* __restrict__ nw,
                                                    const float* __restrict__ dn,
                                                    float* __restrict__ out) {
    __shared__ float tile[TCELLS][197];   // pad 197: conflict-free column reads
    __shared__ float dinv[TCELLS];
    const int t = threadIdx.x;
    const int pg = blockIdx.x >> 8;              // plane index 0..B*3-1 (256 tiles/plane)
    const int c0 = (blockIdx.x & 255) * TCELLS;  // first cell of tile

    const float* src = nw + ((size_t)pg * G2 + c0) * NC;
    for (int i = t; i < TCELLS * NC4; i += 256) {
        const int cell = i / NC4;
        const int cp = i - cell * NC4;
        float4 v = ((const float4*)(src + (size_t)cell * NC))[cp];
        float* dst = &tile[cell][cp * 4];
        dst[0] = v.x; dst[1] = v.y; dst[2] = v.z; dst[3] = v.w;
    }
    if (t < TCELLS) dinv[t] = 1.0f / fmaxf(dn[pg * G2 + c0 + t], 1e-6f);
    __syncthreads();

    float* obase = out + (size_t)pg * NC * G2 + c0;
    for (int i = t; i < TCELLS * NC; i += 256) {
        const int c = i >> 6;
        const int cell = i & 63;
        obase[(size_t)c * G2 + cell] = tile[cell][c] * dinv[cell];
    }
}

// ---------- fallback (direct-to-out channel-major) path ----------

__device__ __forceinline__ void slot_flush(const Slot& s, float* __restrict__ out,
                                           float* __restrict__ den,
                                           size_t outPlaneBase, int denPlaneBase,
                                           int lane) {
    if (s.tag < 0) return;
    if (lane < NC4) {
        size_t base = outPlaneBase + (size_t)(4 * lane) * G2 + (size_t)s.tag;
        unsafeAtomicAdd(out + base,                 s.acc.x);
        unsafeAtomicAdd(out + base + (size_t)G2,    s.acc.y);
        unsafeAtomicAdd(out + base + (size_t)2*G2,  s.acc.z);
        unsafeAtomicAdd(out + base + (size_t)3*G2,  s.acc.w);
    }
    if (lane == 0) unsafeAtomicAdd(den + denPlaneBase + s.tag, s.den);
}

__device__ __forceinline__ void plane_acc(Slot& a, Slot& b, int cell, float alpha,
                                          const float4& av,
                                          float* __restrict__ out, float* __restrict__ den,
                                          size_t outPlaneBase, int denPlaneBase, int lane) {
    if (cell == a.tag) {
        a.acc.x += av.x; a.acc.y += av.y; a.acc.z += av.z; a.acc.w += av.w;
        a.den += alpha;
    } else if (cell == b.tag) {
        b.acc.x += av.x; b.acc.y += av.y; b.acc.z += av.z; b.acc.w += av.w;
        b.den += alpha;
    } else {
        if (b.den > a.den) { Slot t = a; a = b; b = t; }
        slot_flush(b, out, den, outPlaneBase, denPlaneBase, lane);
        b.tag = cell; b.den = alpha; b.acc = av;
    }
}

__global__ __launch_bounds__(256) void splat_kernel(
    const float* __restrict__ gs, const float* __restrict__ sb,
    float* __restrict__ out, float* __restrict__ den,
    int B, int N, int ppw) {
    const int lane = threadIdx.x & 63;
    const long long wave = (long long)blockIdx.x * (blockDim.x >> 6) + (threadIdx.x >> 6);
    const long long totalPts = (long long)B * N;
    long long start = wave * ppw;
    if (start >= totalPts) return;
    long long end = start + ppw;
    if (end > totalPts) end = totalPts;
    const int bb = (int)(start / N);

    const float lo0 = sb[0], hi0 = sb[1];
    const float lo1 = sb[2], hi1 = sb[3];
    const float lo2 = sb[4], hi2 = sb[5];
    const float s0 = 2.0f / (hi0 - lo0);
    const float s1 = 2.0f / (hi1 - lo1);
    const float s2 = 2.0f / (hi2 - lo2);

    const size_t ob0 = ((size_t)(bb * 3 + 0) * NC) * G2;
    const size_t ob1 = ((size_t)(bb * 3 + 1) * NC) * G2;
    const size_t ob2 = ((size_t)(bb * 3 + 2) * NC) * G2;
    const int db0 = (bb * 3 + 0) * G2;
    const int db1 = (bb * 3 + 1) * G2;
    const int db2 = (bb * 3 + 2) * G2;

    const float4 f40 = make_float4(0.f, 0.f, 0.f, 0.f);
    Slot a0{-1, 0.f, f40}, t0{-1, 0.f, f40};
    Slot a1{-1, 0.f, f40}, t1{-1, 0.f, f40};
    Slot a2{-1, 0.f, f40}, t2{-1, 0.f, f40};

    const float4* rows = (const float4*)gs;
    const float4* r0 = rows + (size_t)start * NC4;
    float4 v = (lane < NC4) ? r0[lane] : f40;
    float4 h = r0[0];

    for (long long i = start; i < end; ++i) {
        float4 vn = f40, hn = f40;
        if (i + 1 < end) {
            const float4* rn = rows + (size_t)(i + 1) * NC4;
            vn = (lane < NC4) ? rn[lane] : f40;
            hn = rn[0];
        }
        const float cnx = (h.x - lo0) * s0 - 1.0f;
        const float cny = (h.y - lo1) * s1 - 1.0f;
        const float cnz = (h.z - lo2) * s2 - 1.0f;
        int gx = (int)((cnx * 0.5f + 0.5f) * 127.0f);
        int gy = (int)((cny * 0.5f + 0.5f) * 127.0f);
        int gz = (int)((cnz * 0.5f + 0.5f) * 127.0f);
        gx = min(127, max(0, gx));
        gy = min(127, max(0, gy));
        gz = min(127, max(0, gz));
        const int cxy = __builtin_amdgcn_readfirstlane(gx * GRID_SZ + gy);
        const int cxz = __builtin_amdgcn_readfirstlane(gx * GRID_SZ + gz);
        const int cyz = __builtin_amdgcn_readfirstlane(gy * GRID_SZ + gz);

        const float alpha = 1.0f / (1.0f + __expf(-h.w));

        float4 vv = v;
        if (lane == 0) { vv.x = cnx; vv.y = cny; vv.z = cnz; }
        const float4 av = make_float4(vv.x * alpha, vv.y * alpha, vv.z * alpha, vv.w * alpha);

        plane_acc(a0, t0, cxy, alpha, av, out, den, ob0, db0, lane);
        plane_acc(a1, t1, cxz, alpha, av, out, den, ob1, db1, lane);
        plane_acc(a2, t2, cyz, alpha, av, out, den, ob2, db2, lane);

        v = vn; h = hn;
    }

    slot_flush(a0, out, den, ob0, db0, lane);
    slot_flush(t0, out, den, ob0, db0, lane);
    slot_flush(a1, out, den, ob1, db1, lane);
    slot_flush(t1, out, den, ob1, db1, lane);
    slot_flush(a2, out, den, ob2, db2, lane);
    slot_flush(t2, out, den, ob2, db2, lane);
}

__global__ void zero_kernel(float4* __restrict__ p, long long n4) {
    long long i = (long long)blockIdx.x * blockDim.x + threadIdx.x;
    long long stride = (long long)gridDim.x * blockDim.x;
    const float4 z = make_float4(0.f, 0.f, 0.f, 0.f);
    for (; i < n4; i += stride) p[i] = z;
}

__global__ void normalize_kernel(float* __restrict__ out, const float* __restrict__ den,
                                 int total4) {
    int idx = blockIdx.x * blockDim.x + threadIdx.x;
    const int stride = gridDim.x * blockDim.x;
    for (; idx < total4; idx += stride) {
        float4 v = ((float4*)out)[idx];
        const int e = idx * 4;
        const int cell = e & (G2 - 1);
        const int bp = e / (NC * G2);
        const float4 d = *(const float4*)(den + bp * G2 + cell);
        v.x /= fmaxf(d.x, 1e-6f);
        v.y /= fmaxf(d.y, 1e-6f);
        v.z /= fmaxf(d.z, 1e-6f);
        v.w /= fmaxf(d.w, 1e-6f);
        ((float4*)out)[idx] = v;
    }
}

extern "C" void kernel_launch(void* const* d_in, const int* in_sizes, int n_in,
                              void* d_out, int out_size, void* d_ws, size_t ws_size,
                              hipStream_t stream) {
    const float* gs = (const float*)d_in[0];
    const float* sb = (const float*)d_in[1];
    float* out = (float*)d_out;

    const int B = out_size / (3 * NC * G2);                            // 4
    const long long N = (long long)in_sizes[0] / ((long long)B * NC);  // 131072

    const size_t nwFloats = (size_t)B * 3 * G2 * NC;      // 38.5M
    const size_t dnFloats = (size_t)B * 3 * G2;           // 196K
    const size_t needBytes = (nwFloats + dnFloats) * sizeof(float);    // ~155 MB

    if (ws_size >= needBytes) {
        const long long waves = ((long long)B * N + PPW - 1) / PPW;    // 8192
        const int blocks = (int)((waves + BLK_WAVES - 1) / BLK_WAVES); // 2048

        float* nw = (float*)d_ws;
        float* dn = nw + nwFloats;
        const long long z4 = (long long)(nwFloats + dnFloats) / 4;
        zero_kernel<<<4096, 256, 0, stream>>>((float4*)d_ws, z4);
        splat_cm_kernel<<<blocks, 256, 0, stream>>>(gs, sb, nw, dn, B, (int)N);
        const int xblocks = B * 3 * (G2 / TCELLS);        // 3072
        xpose_kernel<<<xblocks, 256, 0, stream>>>(nw, dn, out);
    } else {
        const int ppw = 64;
        const long long waves = ((long long)B * N) / ppw;
        const int blocks = (int)((waves + 3) / 4);
        float* den = (float*)d_ws;
        const long long out4 = (long long)out_size / 4;
        const long long den4 = (long long)dnFloats / 4;
        zero_kernel<<<2048, 256, 0, stream>>>((float4*)out, out4);
        zero_kernel<<<256, 256, 0, stream>>>((float4*)den, den4);
        splat_kernel<<<blocks, 256, 0, stream>>>(gs, sb, out, den, B, (int)N, ppw);
        normalize_kernel<<<4096, 256, 0, stream>>>(out, den, (int)out4);
    }
}

// Round 5
// 710.166 us; speedup vs baseline: 2.8525x; 2.8525x over previous
//
#include <hip/hip_runtime.h>
#include <math.h>

#define GRID_SZ 128
#define NC 196
#define NC4 49                // NC/4 float4 per row
#define G2 (GRID_SZ*GRID_SZ)  // 16384
#define UPTS 256              // sorted pairs per wave in gather

// ---------------- K1: cell ids + wave-aggregated histogram ----------------

__global__ __launch_bounds__(256) void cellid_hist_kernel(
    const float* __restrict__ gs, const float* __restrict__ sb,
    unsigned short* __restrict__ cellid, unsigned int* __restrict__ hist,
    int B, int N) {
    const long long Q = (long long)B * 3 * N;
    const long long q = (long long)blockIdx.x * blockDim.x + threadIdx.x;
    const bool valid = (q < Q);
    const int lane = threadIdx.x & 63;

    int bin = -1;
    if (valid) {
        const int NP = 3 * N;
        const int b = (int)(q / NP);
        const int r = (int)(q - (long long)b * NP);
        const int p = r / N;
        const int n = r - p * N;

        const float* row = gs + ((size_t)b * N + n) * NC;
        const float x = row[0], y = row[1], z = row[2];

        const float i0 = 1.0f / (sb[1] - sb[0]);
        const float i1 = 1.0f / (sb[3] - sb[2]);
        const float i2 = 1.0f / (sb[5] - sb[4]);
        int gx = (int)((x - sb[0]) * i0 * 127.0f);
        int gy = (int)((y - sb[2]) * i1 * 127.0f);
        int gz = (int)((z - sb[4]) * i2 * 127.0f);
        gx = min(127, max(0, gx));
        gy = min(127, max(0, gy));
        gz = min(127, max(0, gz));

        const int cell = (p == 0) ? (gx * GRID_SZ + gy)
                       : (p == 1) ? (gx * GRID_SZ + gz)
                                  : (gy * GRID_SZ + gz);
        cellid[q] = (unsigned short)cell;
        bin = (b * 3 + p) * G2 + cell;
    }

    unsigned long long todo = __ballot(valid);
    while (todo) {
        const int leader = __ffsll((long long)todo) - 1;
        const int lb = __shfl(bin, leader);
        const unsigned long long match = __ballot(valid && bin == lb);
        if (lane == leader) atomicAdd(&hist[lb], (unsigned)__popcll(match));
        todo &= ~match;
    }
}

// ---------------- K2: 3-phase exclusive scan over NB bins ----------------

__global__ __launch_bounds__(256) void scanA_kernel(const unsigned int* __restrict__ hist,
                                                    unsigned int* __restrict__ cursor,
                                                    unsigned int* __restrict__ partials,
                                                    int NB) {
    __shared__ unsigned int s[256];
    const int t = threadIdx.x;
    const int g = blockIdx.x * 256 + t;
    const unsigned v = (g < NB) ? hist[g] : 0u;
    s[t] = v;
    __syncthreads();
    for (int off = 1; off < 256; off <<= 1) {
        const unsigned u = (t >= off) ? s[t - off] : 0u;
        __syncthreads();
        s[t] += u;
        __syncthreads();
    }
    if (g < NB) cursor[g] = s[t] - v;      // exclusive
    if (t == 255) partials[blockIdx.x] = s[255];
}

__global__ __launch_bounds__(1024) void scanB_kernel(unsigned int* __restrict__ partials,
                                                     int np) {
    __shared__ unsigned int s[1024];
    const int t = threadIdx.x;
    const unsigned v = (t < np) ? partials[t] : 0u;
    s[t] = v;
    __syncthreads();
    for (int off = 1; off < 1024; off <<= 1) {
        const unsigned u = (t >= off) ? s[t - off] : 0u;
        __syncthreads();
        s[t] += u;
        __syncthreads();
    }
    if (t < np) partials[t] = s[t] - v;    // exclusive
}

__global__ __launch_bounds__(256) void scanC_kernel(unsigned int* __restrict__ cursor,
                                                    const unsigned int* __restrict__ partials,
                                                    int NB) {
    const int g = blockIdx.x * 256 + threadIdx.x;
    if (g < NB) cursor[g] += partials[blockIdx.x];
}

// ---------------- K3: wave-aggregated scatter into sorted order ----------------

__global__ __launch_bounds__(256) void scatter_kernel(
    const unsigned short* __restrict__ cellid, unsigned int* __restrict__ cursor,
    unsigned int* __restrict__ order, unsigned short* __restrict__ scell,
    int B, int N) {
    const long long Q = (long long)B * 3 * N;
    const long long q = (long long)blockIdx.x * blockDim.x + threadIdx.x;
    const bool valid = (q < Q);
    const int lane = threadIdx.x & 63;

    int bin = -1, n = 0, cell = 0;
    if (valid) {
        const int NP = 3 * N;
        const int b = (int)(q / NP);
        const int r = (int)(q - (long long)b * NP);
        const int p = r / N;
        n = r - p * N;
        cell = cellid[q];
        bin = (b * 3 + p) * G2 + cell;
    }

    unsigned long long todo = __ballot(valid);
    while (todo) {
        const int leader = __ffsll((long long)todo) - 1;
        const int lb = __shfl(bin, leader);
        const unsigned long long match = __ballot(valid && bin == lb);
        unsigned base = 0;
        if (lane == leader) base = atomicAdd(&cursor[lb], (unsigned)__popcll(match));
        base = __shfl((int)base, leader);
        if (valid && bin == lb) {
            const unsigned rank = (unsigned)__popcll(match & ((1ull << lane) - 1ull));
            order[base + rank] = (unsigned)n;
            scell[base + rank] = (unsigned short)cell;
        }
        todo &= ~match;
    }
}

// ---------------- K4: contiguous gather-reduce over sorted pairs ----------------

__device__ __forceinline__ void flush_bin(int bin, const float4& acc, float den,
                                          float* __restrict__ nw, float* __restrict__ dn,
                                          int lane) {
    if (bin < 0) return;
    if (lane < NC4) {
        float* base = nw + (size_t)bin * NC + 4 * lane;
        unsafeAtomicAdd(base + 0, acc.x);
        unsafeAtomicAdd(base + 1, acc.y);
        unsafeAtomicAdd(base + 2, acc.z);
        unsafeAtomicAdd(base + 3, acc.w);
    } else if (lane == NC4) {
        unsafeAtomicAdd(dn + bin, den);
    }
}

__global__ __launch_bounds__(256) void gather_kernel(
    const float* __restrict__ gs, const float* __restrict__ sb,
    const unsigned int* __restrict__ order, const unsigned short* __restrict__ scell,
    float* __restrict__ nw, float* __restrict__ dn,
    int B, int N) {
    const long long Q = (long long)B * 3 * N;
    const int lane = threadIdx.x & 63;
    const long long wave = (long long)blockIdx.x * (blockDim.x >> 6) + (threadIdx.x >> 6);
    const long long i0 = wave * UPTS;
    if (i0 >= Q) return;
    long long i1 = i0 + UPTS;
    if (i1 > Q) i1 = Q;

    const float lo0 = sb[0], hi0 = sb[1];
    const float lo1 = sb[2], hi1 = sb[3];
    const float lo2 = sb[4], hi2 = sb[5];
    const float s0 = 2.0f / (hi0 - lo0);
    const float s1 = 2.0f / (hi1 - lo1);
    const float s2 = 2.0f / (hi2 - lo2);

    const float4 f40 = make_float4(0.f, 0.f, 0.f, 0.f);
    const float4* rows = (const float4*)gs;

    // pipeline: meta depth-2, row depth-1
    int nA = (int)order[i0];
    int cA = scell[i0];
    int nB_ = 0, cB_ = 0;
    if (i0 + 1 < i1) { nB_ = (int)order[i0 + 1]; cB_ = scell[i0 + 1]; }

    {
        const int secA = (int)(i0 / N);
        const int bA = secA / 3;
        const float4* rA = rows + ((size_t)bA * N + nA) * NC4;
        float4 v = (lane < NC4) ? rA[lane] : f40;
        float4 h = rA[0];

        int curBin = -1;
        float4 acc = f40;
        float accD = 0.f;

        for (long long i = i0; i < i1; ++i) {
            // issue next row load
            float4 vn = f40, hn = f40;
            if (i + 1 < i1) {
                const int secN = (int)((i + 1) / N);
                const int bN = secN / 3;
                const float4* rn = rows + ((size_t)bN * N + nB_) * NC4;
                vn = (lane < NC4) ? rn[lane] : f40;
                hn = rn[0];
            }
            const int cellCur = cA;
            // shift meta, prefetch meta i+2
            nA = nB_; cA = cB_;
            if (i + 2 < i1) { nB_ = (int)order[i + 2]; cB_ = scell[i + 2]; }

            // compute contribution (h uniform across wave)
            const float cnx = (h.x - lo0) * s0 - 1.0f;
            const float cny = (h.y - lo1) * s1 - 1.0f;
            const float cnz = (h.z - lo2) * s2 - 1.0f;
            const float alpha = 1.0f / (1.0f + __expf(-h.w));

            float4 vv = v;
            if (lane == 0) { vv.x = cnx; vv.y = cny; vv.z = cnz; }
            const float4 av = make_float4(vv.x * alpha, vv.y * alpha,
                                          vv.z * alpha, vv.w * alpha);

            const int sec = (int)(i / N);
            const int bin = sec * G2 + cellCur;
            if (bin != curBin) {
                flush_bin(curBin, acc, accD, nw, dn, lane);
                curBin = bin; acc = av; accD = alpha;
            } else {
                acc.x += av.x; acc.y += av.y; acc.z += av.z; acc.w += av.w;
                accD += alpha;
            }

            v = vn; h = hn;
        }
        flush_bin(curBin, acc, accD, nw, dn, lane);
    }
}

// ---------------- K5: transpose + normalize ----------------

#define TCELLS 64
__global__ __launch_bounds__(256) void xpose_kernel(const float* __restrict__ nw,
                                                    const float* __restrict__ dn,
                                                    float* __restrict__ out) {
    __shared__ float tile[TCELLS][197];   // pad: conflict-free column reads
    __shared__ float dinv[TCELLS];
    const int t = threadIdx.x;
    const int pg = blockIdx.x >> 8;              // plane index (256 tiles/plane)
    const int c0 = (blockIdx.x & 255) * TCELLS;

    const float* src = nw + ((size_t)pg * G2 + c0) * NC;
    for (int i = t; i < TCELLS * NC4; i += 256) {
        const int cell = i / NC4;
        const int cp = i - cell * NC4;
        float4 v = ((const float4*)(src + (size_t)cell * NC))[cp];
        float* dst = &tile[cell][cp * 4];
        dst[0] = v.x; dst[1] = v.y; dst[2] = v.z; dst[3] = v.w;
    }
    if (t < TCELLS) dinv[t] = 1.0f / fmaxf(dn[pg * G2 + c0 + t], 1e-6f);
    __syncthreads();

    float* obase = out + (size_t)pg * NC * G2 + c0;
    for (int i = t; i < TCELLS * NC; i += 256) {
        const int c = i >> 6;
        const int cell = i & 63;
        obase[(size_t)c * G2 + cell] = tile[cell][c] * dinv[cell];
    }
}

// ---------------- utility ----------------

__global__ void zero_kernel(float4* __restrict__ p, long long n4) {
    long long i = (long long)blockIdx.x * blockDim.x + threadIdx.x;
    long long stride = (long long)gridDim.x * blockDim.x;
    const float4 z = make_float4(0.f, 0.f, 0.f, 0.f);
    for (; i < n4; i += stride) p[i] = z;
}

// ---------------- fallback (direct channel-major, R1-style) ----------------

struct Slot { int tag; float den; float4 acc; };

__device__ __forceinline__ void slot_flush(const Slot& s, float* __restrict__ out,
                                           float* __restrict__ den,
                                           size_t outPlaneBase, int denPlaneBase, int lane) {
    if (s.tag < 0) return;
    if (lane < NC4) {
        size_t base = outPlaneBase + (size_t)(4 * lane) * G2 + (size_t)s.tag;
        unsafeAtomicAdd(out + base,                s.acc.x);
        unsafeAtomicAdd(out + base + (size_t)G2,   s.acc.y);
        unsafeAtomicAdd(out + base + (size_t)2*G2, s.acc.z);
        unsafeAtomicAdd(out + base + (size_t)3*G2, s.acc.w);
    }
    if (lane == 0) unsafeAtomicAdd(den + denPlaneBase + s.tag, s.den);
}

__device__ __forceinline__ void plane_acc(Slot& a, Slot& b, int cell, float alpha,
                                          const float4& av,
                                          float* __restrict__ out, float* __restrict__ den,
                                          size_t outPlaneBase, int denPlaneBase, int lane) {
    if (cell == a.tag) {
        a.acc.x += av.x; a.acc.y += av.y; a.acc.z += av.z; a.acc.w += av.w; a.den += alpha;
    } else if (cell == b.tag) {
        b.acc.x += av.x; b.acc.y += av.y; b.acc.z += av.z; b.acc.w += av.w; b.den += alpha;
    } else {
        if (b.den > a.den) { Slot t = a; a = b; b = t; }
        slot_flush(b, out, den, outPlaneBase, denPlaneBase, lane);
        b.tag = cell; b.den = alpha; b.acc = av;
    }
}

__global__ __launch_bounds__(256) void splat_kernel(
    const float* __restrict__ gs, const float* __restrict__ sb,
    float* __restrict__ out, float* __restrict__ den, int B, int N, int ppw) {
    const int lane = threadIdx.x & 63;
    const long long wave = (long long)blockIdx.x * (blockDim.x >> 6) + (threadIdx.x >> 6);
    const long long totalPts = (long long)B * N;
    long long start = wave * ppw;
    if (start >= totalPts) return;
    long long end = start + ppw;
    if (end > totalPts) end = totalPts;
    const int bb = (int)(start / N);

    const float lo0 = sb[0], hi0 = sb[1];
    const float lo1 = sb[2], hi1 = sb[3];
    const float lo2 = sb[4], hi2 = sb[5];
    const float s0 = 2.0f / (hi0 - lo0);
    const float s1 = 2.0f / (hi1 - lo1);
    const float s2 = 2.0f / (hi2 - lo2);

    const size_t ob0 = ((size_t)(bb * 3 + 0) * NC) * G2;
    const size_t ob1 = ((size_t)(bb * 3 + 1) * NC) * G2;
    const size_t ob2 = ((size_t)(bb * 3 + 2) * NC) * G2;
    const int db0 = (bb * 3 + 0) * G2;
    const int db1 = (bb * 3 + 1) * G2;
    const int db2 = (bb * 3 + 2) * G2;

    const float4 f40 = make_float4(0.f, 0.f, 0.f, 0.f);
    Slot a0{-1,0.f,f40}, t0{-1,0.f,f40}, a1{-1,0.f,f40}, t1{-1,0.f,f40},
         a2{-1,0.f,f40}, t2{-1,0.f,f40};

    const float4* rows = (const float4*)gs;
    const float4* r0 = rows + (size_t)start * NC4;
    float4 v = (lane < NC4) ? r0[lane] : f40;
    float4 h = r0[0];

    for (long long i = start; i < end; ++i) {
        float4 vn = f40, hn = f40;
        if (i + 1 < end) {
            const float4* rn = rows + (size_t)(i + 1) * NC4;
            vn = (lane < NC4) ? rn[lane] : f40;
            hn = rn[0];
        }
        const float cnx = (h.x - lo0) * s0 - 1.0f;
        const float cny = (h.y - lo1) * s1 - 1.0f;
        const float cnz = (h.z - lo2) * s2 - 1.0f;
        int gx = (int)((cnx * 0.5f + 0.5f) * 127.0f);
        int gy = (int)((cny * 0.5f + 0.5f) * 127.0f);
        int gz = (int)((cnz * 0.5f + 0.5f) * 127.0f);
        gx = min(127, max(0, gx)); gy = min(127, max(0, gy)); gz = min(127, max(0, gz));
        const int cxy = __builtin_amdgcn_readfirstlane(gx * GRID_SZ + gy);
        const int cxz = __builtin_amdgcn_readfirstlane(gx * GRID_SZ + gz);
        const int cyz = __builtin_amdgcn_readfirstlane(gy * GRID_SZ + gz);
        const float alpha = 1.0f / (1.0f + __expf(-h.w));
        float4 vv = v;
        if (lane == 0) { vv.x = cnx; vv.y = cny; vv.z = cnz; }
        const float4 av = make_float4(vv.x*alpha, vv.y*alpha, vv.z*alpha, vv.w*alpha);
        plane_acc(a0, t0, cxy, alpha, av, out, den, ob0, db0, lane);
        plane_acc(a1, t1, cxz, alpha, av, out, den, ob1, db1, lane);
        plane_acc(a2, t2, cyz, alpha, av, out, den, ob2, db2, lane);
        v = vn; h = hn;
    }
    slot_flush(a0, out, den, ob0, db0, lane);
    slot_flush(t0, out, den, ob0, db0, lane);
    slot_flush(a1, out, den, ob1, db1, lane);
    slot_flush(t1, out, den, ob1, db1, lane);
    slot_flush(a2, out, den, ob2, db2, lane);
    slot_flush(t2, out, den, ob2, db2, lane);
}

__global__ void normalize_kernel(float* __restrict__ out, const float* __restrict__ den,
                                 int total4) {
    int idx = blockIdx.x * blockDim.x + threadIdx.x;
    const int stride = gridDim.x * blockDim.x;
    for (; idx < total4; idx += stride) {
        float4 v = ((float4*)out)[idx];
        const int e = idx * 4;
        const int cell = e & (G2 - 1);
        const int bp = e / (NC * G2);
        const float4 d = *(const float4*)(den + bp * G2 + cell);
        v.x /= fmaxf(d.x, 1e-6f);
        v.y /= fmaxf(d.y, 1e-6f);
        v.z /= fmaxf(d.z, 1e-6f);
        v.w /= fmaxf(d.w, 1e-6f);
        ((float4*)out)[idx] = v;
    }
}

// ---------------- launch ----------------

extern "C" void kernel_launch(void* const* d_in, const int* in_sizes, int n_in,
                              void* d_out, int out_size, void* d_ws, size_t ws_size,
                              hipStream_t stream) {
    const float* gs = (const float*)d_in[0];
    const float* sb = (const float*)d_in[1];
    float* out = (float*)d_out;

    const int B = out_size / (3 * NC * G2);                            // 4
    const int N = (int)((long long)in_sizes[0] / ((long long)B * NC)); // 131072
    const long long Q = (long long)B * 3 * N;                          // 1.57M
    const int NB = B * 3 * G2;                                         // 196608

    // workspace layout (floats/units, 256B-ish aligned by construction)
    const size_t nwF = (size_t)NB * NC;          // 38.5M floats
    const size_t dnF = (size_t)NB;               // 196K floats
    size_t off = 0;
    const size_t o_nw = off;      off += nwF * 4;
    const size_t o_dn = off;      off += dnF * 4;
    const size_t o_hist = off;    off += (size_t)NB * 4;
    const size_t o_cur = off;     off += (size_t)NB * 4;
    const size_t o_part = off;    off += 1024 * 4;
    const size_t o_cell = off;    off += ((size_t)Q * 2 + 255) & ~255ull;
    const size_t o_order = off;   off += (size_t)Q * 4;
    const size_t o_scell = off;   off += ((size_t)Q * 2 + 255) & ~255ull;
    const size_t need = off;

    const int nPart = (NB + 255) / 256;          // 768

    if (ws_size >= need && nPart <= 1024) {
        char* ws = (char*)d_ws;
        float* nw = (float*)(ws + o_nw);
        float* dn = (float*)(ws + o_dn);
        unsigned int* hist = (unsigned int*)(ws + o_hist);
        unsigned int* cur = (unsigned int*)(ws + o_cur);
        unsigned int* part = (unsigned int*)(ws + o_part);
        unsigned short* cellid = (unsigned short*)(ws + o_cell);
        unsigned int* order = (unsigned int*)(ws + o_order);
        unsigned short* scell = (unsigned short*)(ws + o_scell);

        // zero nw+dn (contiguous) and hist
        zero_kernel<<<4096, 256, 0, stream>>>((float4*)nw, (long long)(nwF + dnF) / 4);
        zero_kernel<<<256, 256, 0, stream>>>((float4*)hist, (long long)NB / 4);

        const int qBlocks = (int)((Q + 255) / 256);                    // 6144
        cellid_hist_kernel<<<qBlocks, 256, 0, stream>>>(gs, sb, cellid, hist, B, N);

        scanA_kernel<<<nPart, 256, 0, stream>>>(hist, cur, part, NB);
        scanB_kernel<<<1, 1024, 0, stream>>>(part, nPart);
        scanC_kernel<<<nPart, 256, 0, stream>>>(cur, part, NB);

        scatter_kernel<<<qBlocks, 256, 0, stream>>>(cellid, cur, order, scell, B, N);

        const long long gWaves = (Q + UPTS - 1) / UPTS;                // 6144
        const int gBlocks = (int)((gWaves + 3) / 4);                   // 1536
        gather_kernel<<<gBlocks, 256, 0, stream>>>(gs, sb, order, scell, nw, dn, B, N);

        const int xblocks = B * 3 * (G2 / TCELLS);                     // 3072
        xpose_kernel<<<xblocks, 256, 0, stream>>>(nw, dn, out);
    } else {
        // fallback: direct channel-major splat
        float* den = (float*)d_ws;
        const long long out4 = (long long)out_size / 4;
        const long long den4 = (long long)dnF / 4;
        const int ppw = 64;
        const long long waves = ((long long)B * N) / ppw;
        const int blocks = (int)((waves + 3) / 4);
        zero_kernel<<<2048, 256, 0, stream>>>((float4*)out, out4);
        zero_kernel<<<256, 256, 0, stream>>>((float4*)den, den4);
        splat_kernel<<<blocks, 256, 0, stream>>>(gs, sb, out, den, B, N, ppw);
        normalize_kernel<<<4096, 256, 0, stream>>>(out, den, (int)out4);
    }
}

// Round 6
// 706.337 us; speedup vs baseline: 2.8679x; 1.0054x over previous
//
#include <hip/hip_runtime.h>
#include <math.h>

#define GRID_SZ 128
#define NC 196
#define NC4 49                // NC/4 float4 per row
#define G2 (GRID_SZ*GRID_SZ)  // 16384
#define UPTS 256              // sorted pairs per wave in gather (divides N)

// ---------------- K1: cell ids + wave-aggregated histogram ----------------

__global__ __launch_bounds__(256) void cellid_hist_kernel(
    const float* __restrict__ gs, const float* __restrict__ sb,
    unsigned short* __restrict__ cellid, unsigned int* __restrict__ hist,
    int B, int N) {
    const long long Q = (long long)B * 3 * N;
    const long long q = (long long)blockIdx.x * blockDim.x + threadIdx.x;
    const bool valid = (q < Q);
    const int lane = threadIdx.x & 63;

    int bin = -1;
    if (valid) {
        const int NP = 3 * N;
        const int b = (int)(q / NP);
        const int r = (int)(q - (long long)b * NP);
        const int p = r / N;
        const int n = r - p * N;

        const float* row = gs + ((size_t)b * N + n) * NC;
        const float x = row[0], y = row[1], z = row[2];

        const float i0 = 1.0f / (sb[1] - sb[0]);
        const float i1 = 1.0f / (sb[3] - sb[2]);
        const float i2 = 1.0f / (sb[5] - sb[4]);
        int gx = (int)((x - sb[0]) * i0 * 127.0f);
        int gy = (int)((y - sb[2]) * i1 * 127.0f);
        int gz = (int)((z - sb[4]) * i2 * 127.0f);
        gx = min(127, max(0, gx));
        gy = min(127, max(0, gy));
        gz = min(127, max(0, gz));

        const int cell = (p == 0) ? (gx * GRID_SZ + gy)
                       : (p == 1) ? (gx * GRID_SZ + gz)
                                  : (gy * GRID_SZ + gz);
        cellid[q] = (unsigned short)cell;
        bin = (b * 3 + p) * G2 + cell;
    }

    unsigned long long todo = __ballot(valid);
    while (todo) {
        const int leader = __ffsll((long long)todo) - 1;
        const int lb = __shfl(bin, leader);
        const unsigned long long match = __ballot(valid && bin == lb);
        if (lane == leader) atomicAdd(&hist[lb], (unsigned)__popcll(match));
        todo &= ~match;
    }
}

// ---------------- K2: 3-phase exclusive scans (point offsets + compact ids) --------

__global__ __launch_bounds__(256) void scanA_kernel(const unsigned int* __restrict__ hist,
                                                    unsigned int* __restrict__ cursor,
                                                    unsigned int* __restrict__ partials,
                                                    int NB) {
    __shared__ unsigned int s[256];
    const int t = threadIdx.x;
    const int g = blockIdx.x * 256 + t;
    const unsigned v = (g < NB) ? hist[g] : 0u;
    s[t] = v;
    __syncthreads();
    for (int off = 1; off < 256; off <<= 1) {
        const unsigned u = (t >= off) ? s[t - off] : 0u;
        __syncthreads();
        s[t] += u;
        __syncthreads();
    }
    if (g < NB) cursor[g] = s[t] - v;      // exclusive
    if (t == 255) partials[blockIdx.x] = s[255];
}

// occupancy scan: v = (hist>0) ? 1 : 0 -> compact slot ids
__global__ __launch_bounds__(256) void scanA_occ_kernel(const unsigned int* __restrict__ hist,
                                                        int* __restrict__ cid,
                                                        unsigned int* __restrict__ partials,
                                                        int NB) {
    __shared__ unsigned int s[256];
    const int t = threadIdx.x;
    const int g = blockIdx.x * 256 + t;
    const unsigned v = (g < NB && hist[g] > 0u) ? 1u : 0u;
    s[t] = v;
    __syncthreads();
    for (int off = 1; off < 256; off <<= 1) {
        const unsigned u = (t >= off) ? s[t - off] : 0u;
        __syncthreads();
        s[t] += u;
        __syncthreads();
    }
    if (g < NB) cid[g] = (int)(s[t] - v);  // exclusive
    if (t == 255) partials[blockIdx.x] = s[255];
}

__global__ __launch_bounds__(1024) void scanB_kernel(unsigned int* __restrict__ partials,
                                                     int np, unsigned int* __restrict__ total) {
    __shared__ unsigned int s[1024];
    const int t = threadIdx.x;
    const unsigned v = (t < np) ? partials[t] : 0u;
    s[t] = v;
    __syncthreads();
    for (int off = 1; off < 1024; off <<= 1) {
        const unsigned u = (t >= off) ? s[t - off] : 0u;
        __syncthreads();
        s[t] += u;
        __syncthreads();
    }
    if (t < np) partials[t] = s[t] - v;    // exclusive
    if (total != nullptr && t == np - 1) *total = s[t];  // inclusive sum
}

__global__ __launch_bounds__(256) void scanC_kernel(unsigned int* __restrict__ arr,
                                                    const unsigned int* __restrict__ partials,
                                                    int NB) {
    const int g = blockIdx.x * 256 + threadIdx.x;
    if (g < NB) arr[g] += partials[blockIdx.x];
}

__global__ __launch_bounds__(256) void scanC_int_kernel(int* __restrict__ arr,
                                                        const unsigned int* __restrict__ partials,
                                                        int NB) {
    const int g = blockIdx.x * 256 + threadIdx.x;
    if (g < NB) arr[g] += (int)partials[blockIdx.x];
}

// ---------------- zero kernels ----------------

__global__ void zero_kernel(float4* __restrict__ p, long long n4) {
    long long i = (long long)blockIdx.x * blockDim.x + threadIdx.x;
    long long stride = (long long)gridDim.x * blockDim.x;
    const float4 z = make_float4(0.f, 0.f, 0.f, 0.f);
    for (; i < n4; i += stride) p[i] = z;
}

// zero compact accumulators: size read on-device from scan total
__global__ void zero_dyn_kernel(float4* __restrict__ nwc4, float* __restrict__ dnc,
                                const unsigned int* __restrict__ total) {
    const unsigned T = *total;
    const long long n4 = (long long)T * NC4;   // touched rows * 49 float4
    long long i = (long long)blockIdx.x * blockDim.x + threadIdx.x;
    const long long stride = (long long)gridDim.x * blockDim.x;
    const float4 z = make_float4(0.f, 0.f, 0.f, 0.f);
    for (long long k = i; k < n4; k += stride) nwc4[k] = z;
    for (long long k = i; k < (long long)T; k += stride) dnc[k] = 0.f;
}

// ---------------- K3: wave-aggregated scatter into sorted order ----------------

__global__ __launch_bounds__(256) void scatter_kernel(
    const unsigned short* __restrict__ cellid, unsigned int* __restrict__ cursor,
    unsigned int* __restrict__ order, unsigned short* __restrict__ scell,
    int B, int N) {
    const long long Q = (long long)B * 3 * N;
    const long long q = (long long)blockIdx.x * blockDim.x + threadIdx.x;
    const bool valid = (q < Q);
    const int lane = threadIdx.x & 63;

    int bin = -1, n = 0, cell = 0;
    if (valid) {
        const int NP = 3 * N;
        const int b = (int)(q / NP);
        const int r = (int)(q - (long long)b * NP);
        const int p = r / N;
        n = r - p * N;
        cell = cellid[q];
        bin = (b * 3 + p) * G2 + cell;
    }

    unsigned long long todo = __ballot(valid);
    while (todo) {
        const int leader = __ffsll((long long)todo) - 1;
        const int lb = __shfl(bin, leader);
        const unsigned long long match = __ballot(valid && bin == lb);
        unsigned base = 0;
        if (lane == leader) base = atomicAdd(&cursor[lb], (unsigned)__popcll(match));
        base = __shfl((int)base, leader);
        if (valid && bin == lb) {
            const unsigned rank = (unsigned)__popcll(match & ((1ull << lane) - 1ull));
            order[base + rank] = (unsigned)n;
            scell[base + rank] = (unsigned short)cell;
        }
        todo &= ~match;
    }
}

// ---------------- K4: contiguous gather-reduce (compact accumulators) ----------------

__device__ __forceinline__ void flush_bin_c(int cell, const int* __restrict__ cidSec,
                                            const float4& acc, float den,
                                            float* __restrict__ nwc, float* __restrict__ dnc,
                                            int lane) {
    if (cell < 0) return;
    const int cc = cidSec[cell];
    if (lane < NC4) {
        float* base = nwc + (size_t)cc * NC + 4 * lane;
        unsafeAtomicAdd(base + 0, acc.x);
        unsafeAtomicAdd(base + 1, acc.y);
        unsafeAtomicAdd(base + 2, acc.z);
        unsafeAtomicAdd(base + 3, acc.w);
    } else if (lane == NC4) {
        unsafeAtomicAdd(dnc + cc, den);
    }
}

__global__ __launch_bounds__(256) void gather_kernel(
    const float* __restrict__ gs, const float* __restrict__ sb,
    const unsigned int* __restrict__ order, const unsigned short* __restrict__ scell,
    const int* __restrict__ cid,
    float* __restrict__ nwc, float* __restrict__ dnc,
    int N, long long Q) {
    const int lane = threadIdx.x & 63;
    const long long wave = (long long)blockIdx.x * (blockDim.x >> 6) + (threadIdx.x >> 6);
    const long long i0 = wave * UPTS;
    if (i0 >= Q) return;
    const int cnt = (int)((i0 + UPTS <= Q) ? UPTS : (Q - i0));

    // UPTS divides N -> a chunk never crosses a (batch,plane) section boundary
    const int sec = (int)(i0 / N);            // wave-constant
    const int b = sec / 3;                    // wave-constant
    const float4* brows = (const float4*)gs + (size_t)b * N * NC4;
    const int* cidSec = cid + sec * G2;

    const float lo0 = sb[0], hi0 = sb[1];
    const float lo1 = sb[2], hi1 = sb[3];
    const float lo2 = sb[4], hi2 = sb[5];
    const float s0 = 2.0f / (hi0 - lo0);
    const float s1 = 2.0f / (hi1 - lo1);
    const float s2 = 2.0f / (hi2 - lo2);

    const float4 f40 = make_float4(0.f, 0.f, 0.f, 0.f);
    const unsigned int* ord = order + i0;
    const unsigned short* scl = scell + i0;

    int n0 = (int)ord[0];
    int c0_ = (int)scl[0];
    int n1 = 0, c1_ = 0;
    if (cnt > 1) { n1 = (int)ord[1]; c1_ = (int)scl[1]; }

    float4 v, h;
    {
        const float4* r = brows + (size_t)((unsigned)n0 * (unsigned)NC4);
        v = (lane < NC4) ? r[lane] : f40;
        h = r[0];
    }

    int curCell = -1;
    float4 acc = f40;
    float accD = 0.f;

    for (int j = 0; j < cnt; ++j) {
        float4 vn = f40, hn = f40;
        if (j + 1 < cnt) {
            const float4* rn = brows + (size_t)((unsigned)n1 * (unsigned)NC4);
            vn = (lane < NC4) ? rn[lane] : f40;
            hn = rn[0];
        }
        const int cellCur = c0_;
        n0 = n1; c0_ = c1_;
        if (j + 2 < cnt) { n1 = (int)ord[j + 2]; c1_ = (int)scl[j + 2]; }

        const float cnx = (h.x - lo0) * s0 - 1.0f;
        const float cny = (h.y - lo1) * s1 - 1.0f;
        const float cnz = (h.z - lo2) * s2 - 1.0f;
        const float alpha = 1.0f / (1.0f + __expf(-h.w));

        float4 vv = v;
        if (lane == 0) { vv.x = cnx; vv.y = cny; vv.z = cnz; }
        const float4 av = make_float4(vv.x * alpha, vv.y * alpha, vv.z * alpha, vv.w * alpha);

        if (cellCur != curCell) {
            flush_bin_c(curCell, cidSec, acc, accD, nwc, dnc, lane);
            curCell = cellCur; acc = av; accD = alpha;
        } else {
            acc.x += av.x; acc.y += av.y; acc.z += av.z; acc.w += av.w;
            accD += alpha;
        }

        v = vn; h = hn;
    }
    flush_bin_c(curCell, cidSec, acc, accD, nwc, dnc, lane);
}

// ---------------- K5: transpose + normalize from compact ----------------

#define TCELLS 64
__global__ __launch_bounds__(256) void xpose_c_kernel(
    const float* __restrict__ nwc, const float* __restrict__ dnc,
    const int* __restrict__ cid, const unsigned int* __restrict__ hist,
    float* __restrict__ out) {
    __shared__ float tile[TCELLS][197];   // pad: conflict-free column reads
    __shared__ float dinv[TCELLS];
    __shared__ int scid[TCELLS];
    const int t = threadIdx.x;
    const int pg = blockIdx.x >> 8;              // plane index (256 tiles/plane)
    const int c0 = (blockIdx.x & 255) * TCELLS;

    if (t < TCELLS) {
        const int bin = pg * G2 + c0 + t;
        const int cc = (hist[bin] > 0u) ? cid[bin] : -1;
        scid[t] = cc;
        dinv[t] = (cc >= 0) ? 1.0f / fmaxf(dnc[cc], 1e-6f) : 0.0f;
    }
    __syncthreads();

    const float4 f40 = make_float4(0.f, 0.f, 0.f, 0.f);
    for (int i = t; i < TCELLS * NC4; i += 256) {
        const int cell = i / NC4;
        const int cp = i - cell * NC4;
        const int cc = scid[cell];
        float4 v = (cc >= 0) ? ((const float4*)(nwc + (size_t)cc * NC))[cp] : f40;
        float* dst = &tile[cell][cp * 4];
        dst[0] = v.x; dst[1] = v.y; dst[2] = v.z; dst[3] = v.w;
    }
    __syncthreads();

    float* obase = out + (size_t)pg * NC * G2 + c0;
    for (int i = t; i < TCELLS * NC; i += 256) {
        const int c = i >> 6;
        const int cell = i & 63;
        obase[(size_t)c * G2 + cell] = tile[cell][c] * dinv[cell];
    }
}

// ---------------- fallback (direct channel-major, R1-style) ----------------

struct Slot { int tag; float den; float4 acc; };

__device__ __forceinline__ void slot_flush(const Slot& s, float* __restrict__ out,
                                           float* __restrict__ den,
                                           size_t outPlaneBase, int denPlaneBase, int lane) {
    if (s.tag < 0) return;
    if (lane < NC4) {
        size_t base = outPlaneBase + (size_t)(4 * lane) * G2 + (size_t)s.tag;
        unsafeAtomicAdd(out + base,                s.acc.x);
        unsafeAtomicAdd(out + base + (size_t)G2,   s.acc.y);
        unsafeAtomicAdd(out + base + (size_t)2*G2, s.acc.z);
        unsafeAtomicAdd(out + base + (size_t)3*G2, s.acc.w);
    }
    if (lane == 0) unsafeAtomicAdd(den + denPlaneBase + s.tag, s.den);
}

__device__ __forceinline__ void plane_acc(Slot& a, Slot& b, int cell, float alpha,
                                          const float4& av,
                                          float* __restrict__ out, float* __restrict__ den,
                                          size_t outPlaneBase, int denPlaneBase, int lane) {
    if (cell == a.tag) {
        a.acc.x += av.x; a.acc.y += av.y; a.acc.z += av.z; a.acc.w += av.w; a.den += alpha;
    } else if (cell == b.tag) {
        b.acc.x += av.x; b.acc.y += av.y; b.acc.z += av.z; b.acc.w += av.w; b.den += alpha;
    } else {
        if (b.den > a.den) { Slot t = a; a = b; b = t; }
        slot_flush(b, out, den, outPlaneBase, denPlaneBase, lane);
        b.tag = cell; b.den = alpha; b.acc = av;
    }
}

__global__ __launch_bounds__(256) void splat_kernel(
    const float* __restrict__ gs, const float* __restrict__ sb,
    float* __restrict__ out, float* __restrict__ den, int B, int N, int ppw) {
    const int lane = threadIdx.x & 63;
    const long long wave = (long long)blockIdx.x * (blockDim.x >> 6) + (threadIdx.x >> 6);
    const long long totalPts = (long long)B * N;
    long long start = wave * ppw;
    if (start >= totalPts) return;
    long long end = start + ppw;
    if (end > totalPts) end = totalPts;
    const int bb = (int)(start / N);

    const float lo0 = sb[0], hi0 = sb[1];
    const float lo1 = sb[2], hi1 = sb[3];
    const float lo2 = sb[4], hi2 = sb[5];
    const float s0 = 2.0f / (hi0 - lo0);
    const float s1 = 2.0f / (hi1 - lo1);
    const float s2 = 2.0f / (hi2 - lo2);

    const size_t ob0 = ((size_t)(bb * 3 + 0) * NC) * G2;
    const size_t ob1 = ((size_t)(bb * 3 + 1) * NC) * G2;
    const size_t ob2 = ((size_t)(bb * 3 + 2) * NC) * G2;
    const int db0 = (bb * 3 + 0) * G2;
    const int db1 = (bb * 3 + 1) * G2;
    const int db2 = (bb * 3 + 2) * G2;

    const float4 f40 = make_float4(0.f, 0.f, 0.f, 0.f);
    Slot a0{-1,0.f,f40}, t0{-1,0.f,f40}, a1{-1,0.f,f40}, t1{-1,0.f,f40},
         a2{-1,0.f,f40}, t2{-1,0.f,f40};

    const float4* rows = (const float4*)gs;
    const float4* r0 = rows + (size_t)start * NC4;
    float4 v = (lane < NC4) ? r0[lane] : f40;
    float4 h = r0[0];

    for (long long i = start; i < end; ++i) {
        float4 vn = f40, hn = f40;
        if (i + 1 < end) {
            const float4* rn = rows + (size_t)(i + 1) * NC4;
            vn = (lane < NC4) ? rn[lane] : f40;
            hn = rn[0];
        }
        const float cnx = (h.x - lo0) * s0 - 1.0f;
        const float cny = (h.y - lo1) * s1 - 1.0f;
        const float cnz = (h.z - lo2) * s2 - 1.0f;
        int gx = (int)((cnx * 0.5f + 0.5f) * 127.0f);
        int gy = (int)((cny * 0.5f + 0.5f) * 127.0f);
        int gz = (int)((cnz * 0.5f + 0.5f) * 127.0f);
        gx = min(127, max(0, gx)); gy = min(127, max(0, gy)); gz = min(127, max(0, gz));
        const int cxy = __builtin_amdgcn_readfirstlane(gx * GRID_SZ + gy);
        const int cxz = __builtin_amdgcn_readfirstlane(gx * GRID_SZ + gz);
        const int cyz = __builtin_amdgcn_readfirstlane(gy * GRID_SZ + gz);
        const float alpha = 1.0f / (1.0f + __expf(-h.w));
        float4 vv = v;
        if (lane == 0) { vv.x = cnx; vv.y = cny; vv.z = cnz; }
        const float4 av = make_float4(vv.x*alpha, vv.y*alpha, vv.z*alpha, vv.w*alpha);
        plane_acc(a0, t0, cxy, alpha, av, out, den, ob0, db0, lane);
        plane_acc(a1, t1, cxz, alpha, av, out, den, ob1, db1, lane);
        plane_acc(a2, t2, cyz, alpha, av, out, den, ob2, db2, lane);
        v = vn; h = hn;
    }
    slot_flush(a0, out, den, ob0, db0, lane);
    slot_flush(t0, out, den, ob0, db0, lane);
    slot_flush(a1, out, den, ob1, db1, lane);
    slot_flush(t1, out, den, ob1, db1, lane);
    slot_flush(a2, out, den, ob2, db2, lane);
    slot_flush(t2, out, den, ob2, db2, lane);
}

__global__ void normalize_kernel(float* __restrict__ out, const float* __restrict__ den,
                                 int total4) {
    int idx = blockIdx.x * blockDim.x + threadIdx.x;
    const int stride = gridDim.x * blockDim.x;
    for (; idx < total4; idx += stride) {
        float4 v = ((float4*)out)[idx];
        const int e = idx * 4;
        const int cell = e & (G2 - 1);
        const int bp = e / (NC * G2);
        const float4 d = *(const float4*)(den + bp * G2 + cell);
        v.x /= fmaxf(d.x, 1e-6f);
        v.y /= fmaxf(d.y, 1e-6f);
        v.z /= fmaxf(d.z, 1e-6f);
        v.w /= fmaxf(d.w, 1e-6f);
        ((float4*)out)[idx] = v;
    }
}

// ---------------- launch ----------------

extern "C" void kernel_launch(void* const* d_in, const int* in_sizes, int n_in,
                              void* d_out, int out_size, void* d_ws, size_t ws_size,
                              hipStream_t stream) {
    const float* gs = (const float*)d_in[0];
    const float* sb = (const float*)d_in[1];
    float* out = (float*)d_out;

    const int B = out_size / (3 * NC * G2);                            // 4
    const int N = (int)((long long)in_sizes[0] / ((long long)B * NC)); // 131072
    const long long Q = (long long)B * 3 * N;                          // 1.57M
    const int NB = B * 3 * G2;                                         // 196608

    const size_t nwF = (size_t)NB * NC;          // compact worst case = full
    const size_t dnF = (size_t)NB;
    size_t off = 0;
    const size_t o_nw = off;     off += nwF * 4;
    const size_t o_dn = off;     off += dnF * 4;
    const size_t o_hist = off;   off += (size_t)NB * 4;
    const size_t o_cur = off;    off += (size_t)NB * 4;
    const size_t o_cid = off;    off += (size_t)NB * 4;
    const size_t o_part = off;   off += 1024 * 4;
    const size_t o_part2 = off;  off += 1024 * 4;
    const size_t o_total = off;  off += 256;
    const size_t o_cell = off;   off += ((size_t)Q * 2 + 255) & ~255ull;
    const size_t o_order = off;  off += (size_t)Q * 4;
    const size_t o_scell = off;  off += ((size_t)Q * 2 + 255) & ~255ull;
    const size_t need = off;

    const int nPart = (NB + 255) / 256;          // 768

    if (ws_size >= need && nPart <= 1024 && (N % UPTS) == 0) {
        char* ws = (char*)d_ws;
        float* nwc = (float*)(ws + o_nw);
        float* dnc = (float*)(ws + o_dn);
        unsigned int* hist = (unsigned int*)(ws + o_hist);
        unsigned int* cur = (unsigned int*)(ws + o_cur);
        int* cid = (int*)(ws + o_cid);
        unsigned int* part = (unsigned int*)(ws + o_part);
        unsigned int* part2 = (unsigned int*)(ws + o_part2);
        unsigned int* total = (unsigned int*)(ws + o_total);
        unsigned short* cellid = (unsigned short*)(ws + o_cell);
        unsigned int* order = (unsigned int*)(ws + o_order);
        unsigned short* scell = (unsigned short*)(ws + o_scell);

        zero_kernel<<<256, 256, 0, stream>>>((float4*)hist, (long long)NB / 4);

        const int qBlocks = (int)((Q + 255) / 256);                    // 6144
        cellid_hist_kernel<<<qBlocks, 256, 0, stream>>>(gs, sb, cellid, hist, B, N);

        scanA_kernel<<<nPart, 256, 0, stream>>>(hist, cur, part, NB);
        scanA_occ_kernel<<<nPart, 256, 0, stream>>>(hist, cid, part2, NB);
        scanB_kernel<<<1, 1024, 0, stream>>>(part, nPart, nullptr);
        scanB_kernel<<<1, 1024, 0, stream>>>(part2, nPart, total);
        scanC_kernel<<<nPart, 256, 0, stream>>>(cur, part, NB);
        scanC_int_kernel<<<nPart, 256, 0, stream>>>(cid, part2, NB);

        zero_dyn_kernel<<<2048, 256, 0, stream>>>((float4*)nwc, dnc, total);

        scatter_kernel<<<qBlocks, 256, 0, stream>>>(cellid, cur, order, scell, B, N);

        const long long gWaves = (Q + UPTS - 1) / UPTS;                // 6144
        const int gBlocks = (int)((gWaves + 3) / 4);                   // 1536
        gather_kernel<<<gBlocks, 256, 0, stream>>>(gs, sb, order, scell, cid,
                                                   nwc, dnc, N, Q);

        const int xblocks = B * 3 * (G2 / TCELLS);                     // 3072
        xpose_c_kernel<<<xblocks, 256, 0, stream>>>(nwc, dnc, cid, hist, out);
    } else {
        float* den = (float*)d_ws;
        const long long out4 = (long long)out_size / 4;
        const long long den4 = (long long)dnF / 4;
        const int ppw = 64;
        const long long waves = ((long long)B * N) / ppw;
        const int blocks = (int)((waves + 3) / 4);
        zero_kernel<<<2048, 256, 0, stream>>>((float4*)out, out4);
        zero_kernel<<<256, 256, 0, stream>>>((float4*)den, den4);
        splat_kernel<<<blocks, 256, 0, stream>>>(gs, sb, out, den, B, N, ppw);
        normalize_kernel<<<4096, 256, 0, stream>>>(out, den, (int)out4);
    }
}